// Round 13
// baseline (640.256 us; speedup 1.0000x reference)
//
#include <hip/hip_runtime.h>
#include <hip/hip_bf16.h>

#define NODES 100000
#define SCAN_B 200
#define CHUNK 500

typedef __attribute__((ext_vector_type(4))) float f4v;
typedef __attribute__((ext_vector_type(8))) short bfx8;
typedef __attribute__((ext_vector_type(4))) float f32x4;
typedef unsigned short ushort_t;
typedef unsigned int uint_t;

__device__ __forceinline__ ushort_t f2b(float f) {
  union { float f; uint_t u; } v; v.f = f;
  return (ushort_t)((v.u + 0x7fffu + ((v.u >> 16) & 1u)) >> 16);
}
__device__ __forceinline__ float b2f(ushort_t h) {
  union { uint_t u; float f; } v; v.u = ((uint_t)h) << 16;
  return v.f;
}
// packed pair via compiler-fused v_cvt_pk_bf16_f32
__device__ __forceinline__ uint_t pk2(float a, float b) {
  union { __hip_bfloat16 h; ushort_t u; } lo, hi;
  lo.h = __float2bfloat16(a);
  hi.h = __float2bfloat16(b);
  return (uint_t)lo.u | ((uint_t)hi.u << 16);
}

// h1-slot permutation: slot r (GEMM1 D order) -> actual n1 (GEMM2 k order)
__device__ __forceinline__ int permn1(int r) {
  int t = r >> 4, g = (r >> 2) & 3, p = (r >> 1) & 1, e = r & 1;
  int w = 2 * (t & 1) + p;
  return 32 * (t >> 1) + 8 * (g ^ w) + 2 * w + e;
}

#define MFMA16(A, B, C) __builtin_amdgcn_mfma_f32_16x16x32_bf16((A), (B), (C), 0, 0, 0)

// ---------------- graph prep ----------------

__global__ void count_deg(const int* __restrict__ dst, int* __restrict__ deg, int E) {
  int i = blockIdx.x * 256 + threadIdx.x;
  if (i < E) atomicAdd(&deg[dst[i]], 1);
}

__global__ void dinv_k(const int* __restrict__ deg, float* __restrict__ dinv, int n) {
  int i = blockIdx.x * 256 + threadIdx.x;
  if (i < n) dinv[i] = 1.0f / sqrtf((float)(deg[i] + 1));
}

__global__ void scan_sum(const int* __restrict__ deg, int* __restrict__ bsum) {
  __shared__ int sh[256];
  int b = blockIdx.x, t = threadIdx.x;
  int base = b * CHUNK;
  int v = 0;
  for (int i = t; i < CHUNK; i += 256) v += deg[base + i];
  sh[t] = v;
  __syncthreads();
  for (int s = 128; s > 0; s >>= 1) {
    if (t < s) sh[t] += sh[t + s];
    __syncthreads();
  }
  if (t == 0) bsum[b] = sh[0];
}

__global__ void scan_top(int* __restrict__ bsum) {
  __shared__ int sh[SCAN_B];
  int t = threadIdx.x;
  if (t < SCAN_B) sh[t] = bsum[t];
  __syncthreads();
  if (t == 0) {
    int run = 0;
    for (int i = 0; i < SCAN_B; ++i) { int x = sh[i]; sh[i] = run; run += x; }
  }
  __syncthreads();
  if (t < SCAN_B) bsum[t] = sh[t];
}

__global__ void scan_out(const int* __restrict__ deg, const int* __restrict__ bsum,
                         int* __restrict__ row_start, int E) {
  __shared__ int sh[CHUNK];
  int b = blockIdx.x, t = threadIdx.x;
  int base = b * CHUNK;
  for (int i = t; i < CHUNK; i += 256) sh[i] = deg[base + i];
  __syncthreads();
  if (t == 0) {
    int run = bsum[b];
    for (int i = 0; i < CHUNK; ++i) { int x = sh[i]; sh[i] = run; run += x; }
  }
  __syncthreads();
  for (int i = t; i < CHUNK; i += 256) row_start[base + i] = sh[i];
  if (b == SCAN_B - 1 && t == 0) row_start[NODES] = E;
}

__global__ void fill_csr(const int* __restrict__ src, const int* __restrict__ dst,
                         const int* __restrict__ row_start, int* __restrict__ cursor,
                         int* __restrict__ csr, int E) {
  int i = blockIdx.x * 256 + threadIdx.x;
  if (i < E) {
    int d = dst[i];
    int p = atomicAdd(&cursor[d], 1);
    csr[row_start[d] + p] = src[i];
  }
}

// pack GEMM2 weight frags into global (lane-ordered, 16B per lane entry)
__global__ void pack_wf2(const float* __restrict__ Wp2, ushort_t* __restrict__ wf2g) {
  int idx = blockIdx.x * 256 + threadIdx.x;  // 0..1023
  if (idx >= 1024) return;
  int l = idx & 63, fk = idx >> 6;
  int t2 = fk >> 2, kk = fk & 3;
  int lq = l & 15, lg = l >> 4;
#pragma unroll
  for (int j = 0; j < 8; ++j)
    wf2g[idx * 8 + j] = f2b(Wp2[(kk * 32 + lg * 8 + j) * 64 + t2 * 16 + lq]);
}

// ---------------- conv path: split-bf16 MFMA GEMM ----------------
template <int K>
__global__ __launch_bounds__(256) void conv_gemm(
    const float* __restrict__ A, const float* __restrict__ W,
    const float* __restrict__ dinv, float* __restrict__ out, int n) {
  constexpr int KT = K / 32;
  constexpr int SEGS = K / 8;
  __shared__ __align__(16) ushort_t lhi[32 * K];
  __shared__ __align__(16) ushort_t llo[32 * K];

  int tid = threadIdx.x;
  int lane = tid & 63, wave = tid >> 6;
  int q = lane & 15, g = lane >> 4;
  int c0 = wave * 16;
  int r0 = blockIdx.x * 32;

  bfx8 bhi[KT], blo[KT];
#pragma unroll
  for (int kt = 0; kt < KT; ++kt) {
    bfx8 h, l;
#pragma unroll
    for (int j = 0; j < 8; ++j) {
      float w = W[(size_t)(kt * 32 + g * 8 + j) * 64 + c0 + q];
      ushort_t hb = f2b(w);
      float lo = w - b2f(hb);
      h[j] = (short)hb;
      l[j] = (short)f2b(lo);
    }
    bhi[kt] = h;
    blo[kt] = l;
  }

  for (int idx = tid; idx < 32 * SEGS; idx += 256) {
    int row = idx / SEGS, s = idx % SEGS;
    const float* p = A + (size_t)(r0 + row) * K + s * 8;
    f4v v0 = *(const f4v*)p;
    f4v v1 = *(const f4v*)(p + 4);
    bfx8 h8, l8;
#pragma unroll
    for (int j = 0; j < 4; ++j) {
      ushort_t hb = f2b(v0[j]);
      h8[j] = (short)hb;
      l8[j] = (short)f2b(v0[j] - b2f(hb));
      ushort_t hb1 = f2b(v1[j]);
      h8[4 + j] = (short)hb1;
      l8[4 + j] = (short)f2b(v1[j] - b2f(hb1));
    }
    int boff = row * (K * 2) + ((s * 16) ^ ((row & 7) << 4));
    *(bfx8*)((char*)lhi + boff) = h8;
    *(bfx8*)((char*)llo + boff) = l8;
  }
  __syncthreads();

  f32x4 hh[2], hl[2], lh[2];
#pragma unroll
  for (int rt = 0; rt < 2; ++rt) {
    hh[rt] = (f32x4){0.f, 0.f, 0.f, 0.f};
    hl[rt] = (f32x4){0.f, 0.f, 0.f, 0.f};
    lh[rt] = (f32x4){0.f, 0.f, 0.f, 0.f};
  }
#pragma unroll
  for (int kt = 0; kt < KT; ++kt) {
#pragma unroll
    for (int rt = 0; rt < 2; ++rt) {
      int row = rt * 16 + q;
      int boff = row * (K * 2) + (((kt * 64 + g * 16)) ^ ((row & 7) << 4));
      bfx8 ah = *(const bfx8*)((const char*)lhi + boff);
      bfx8 al = *(const bfx8*)((const char*)llo + boff);
      hh[rt] = MFMA16(ah, bhi[kt], hh[rt]);
      hl[rt] = MFMA16(ah, blo[kt], hl[rt]);
      lh[rt] = MFMA16(al, bhi[kt], lh[rt]);
    }
  }

#pragma unroll
  for (int rt = 0; rt < 2; ++rt) {
    f32x4 s = hh[rt] + hl[rt] + lh[rt];
#pragma unroll
    for (int j = 0; j < 4; ++j) {
      int row = r0 + rt * 16 + g * 4 + j;
      if (row < n) out[(size_t)row * 64 + c0 + q] = s[j] * dinv[row];
    }
  }
}

// out[i][c] = relu( dinv[i] * (P[i][c] + sum_{s in nbr(i)} P[s][c]) + bias[c] )
__global__ void agg_k(const float* __restrict__ P, const int* __restrict__ row_start,
                      const int* __restrict__ csr, const float* __restrict__ dinv,
                      const float* __restrict__ bias, float* __restrict__ out,
                      ushort_t* __restrict__ zb, int n) {
  int wave = threadIdx.x >> 6, lane = threadIdx.x & 63;
  int i = blockIdx.x * 4 + wave;
  if (i >= n) return;
  const float* Pl = P + lane;
  float a0 = Pl[(size_t)i * 64];
  float a1 = 0.f, a2 = 0.f, a3 = 0.f;
  int beg = row_start[i], end = row_start[i + 1];
  int j = beg;
  for (; j + 8 <= end; j += 8) {
    int s0 = csr[j + 0], s1 = csr[j + 1], s2 = csr[j + 2], s3 = csr[j + 3];
    int s4 = csr[j + 4], s5 = csr[j + 5], s6 = csr[j + 6], s7 = csr[j + 7];
    float v0 = Pl[(size_t)s0 * 64];
    float v1 = Pl[(size_t)s1 * 64];
    float v2 = Pl[(size_t)s2 * 64];
    float v3 = Pl[(size_t)s3 * 64];
    float v4 = Pl[(size_t)s4 * 64];
    float v5 = Pl[(size_t)s5 * 64];
    float v6 = Pl[(size_t)s6 * 64];
    float v7 = Pl[(size_t)s7 * 64];
    a0 += v0; a1 += v1; a2 += v2; a3 += v3;
    a0 += v4; a1 += v5; a2 += v6; a3 += v7;
  }
  if (j + 4 <= end) {
    int s0 = csr[j + 0], s1 = csr[j + 1], s2 = csr[j + 2], s3 = csr[j + 3];
    float v0 = Pl[(size_t)s0 * 64];
    float v1 = Pl[(size_t)s1 * 64];
    float v2 = Pl[(size_t)s2 * 64];
    float v3 = Pl[(size_t)s3 * 64];
    a0 += v0; a1 += v1; a2 += v2; a3 += v3;
    j += 4;
  }
  for (; j < end; ++j) a1 += Pl[(size_t)csr[j] * 64];
  float acc = (a0 + a1) + (a2 + a3);
  float v = fmaxf(acc * dinv[i] + bias[lane], 0.0f);
  out[(size_t)i * 64 + lane] = v;
  if (zb) zb[(size_t)i * 64 + lane] = f2b(v);
}

// ---------------- edge MLP (merged pos+neg, WF2 via global/L2) ----------------
// 16 edges/wave-iter, 0 bank conflicts, 2-deep prefetch, 1024-thr blocks.
// r12 analysis: LDS pipe was the top consumer (48 ds_read_b128/iter x ~12cyc
// = 77% of runtime). GEMM2 weight frags (16 reads/iter) now come from a
// packed GLOBAL table (16KB, L1/L2-resident, coalesced dwordx4) -> LDS work
// -33%, VMEM pipe has headroom (HBM 16%). LDS 50->34KB keeps 2 blk/CU.
__global__ __launch_bounds__(1024) void mlp_kernel(
    const int* __restrict__ ei, const int* __restrict__ nei,
    const ushort_t* __restrict__ zb, const ushort_t* __restrict__ wf2g,
    const float* __restrict__ Wp1, const float* __restrict__ bp1,
    const float* __restrict__ bp2, const float* __restrict__ Wp3,
    const float* __restrict__ bp3,
    float* __restrict__ pos, float* __restrict__ neg,
    int E, int gridHalf) {
  __shared__ __align__(16) char WT1[32768];   // Wp1 A-frags [kk*8+t][lane]*16B
  __shared__ __align__(16) float Lb1[128];    // bp1 permuted to slot order
  __shared__ __align__(16) float Lb2[64];
  __shared__ __align__(16) float Lw3[64];

  int tid = threadIdx.x;
  int lane = tid & 63, wave = tid >> 6;   // wave in [0,16)
  int q = lane & 15, g = lane >> 4;

  for (int idx = tid; idx < 2048; idx += 1024) {
    int l = idx & 63, f = idx >> 6;
    int t = f & 7, kk = f >> 3;
    int lq = l & 15, lg = l >> 4;
    int n1 = permn1(t * 16 + lq);
    bfx8 v;
#pragma unroll
    for (int j = 0; j < 8; ++j)
      v[j] = (short)f2b(Wp1[(kk * 32 + lg * 8 + j) * 128 + n1]);
    *(bfx8*)(WT1 + idx * 16) = v;
  }
  if (tid < 128) Lb1[tid] = bp1[permn1(tid)];
  if (tid < 64) { Lb2[tid] = bp2[tid]; Lw3[tid] = Wp3[tid]; }
  __syncthreads();

  float bp3v = bp3[0];

  int side = (blockIdx.x >= gridHalf) ? 1 : 0;
  const int* eip = side ? nei : ei;
  float* outp = side ? neg : pos;
  int bb = blockIdx.x - side * gridHalf;

  int nbt = E >> 8;              // 256-edge block-tiles (16 waves x 16)
  int bt0 = bb << 2;             // 4 consecutive tiles per block
  int ewq = (wave << 4) + q;     // edge offset within tile [0,256)

  int si[6], di[6];
  bfx8 af[4], afn[4];

  {
    int e = ((bt0 + 0) < nbt) ? (((bt0 + 0) << 8) + ewq) : 0;
    si[0] = eip[e]; di[0] = eip[E + e];
  }
  {
    int e = ((bt0 + 1) < nbt) ? (((bt0 + 1) << 8) + ewq) : 0;
    si[1] = eip[e]; di[1] = eip[E + e];
  }
#pragma unroll
  for (int kk = 0; kk < 4; ++kk) {
    int node = (kk < 2) ? si[0] : di[0];
    af[kk] = *(const bfx8*)(zb + (size_t)node * 64 + ((kk & 1) << 5) + (g << 3));
  }

#pragma unroll
  for (int it = 0; it < 4; ++it) {
    if (bt0 + it < nbt) {
      // prefetch indices for it+2
      if (it + 2 < 4) {
        int e = ((bt0 + it + 2) < nbt) ? (((bt0 + it + 2) << 8) + ewq) : 0;
        si[it + 2] = eip[e]; di[it + 2] = eip[E + e];
      }
      // prefetch features for it+1 (indices issued one iter ago)
      if (it + 1 < 4 && (bt0 + it + 1) < nbt) {
#pragma unroll
        for (int kk = 0; kk < 4; ++kk) {
          int node = (kk < 2) ? si[it + 1] : di[it + 1];
          afn[kk] = *(const bfx8*)(zb + (size_t)node * 64 + ((kk & 1) << 5) + (g << 3));
        }
      } else {
#pragma unroll
        for (int kk = 0; kk < 4; ++kk) afn[kk] = af[kk];
      }

      f32x4 acc2[4];
#pragma unroll
      for (int t2 = 0; t2 < 4; ++t2) acc2[t2] = (f32x4){0.f, 0.f, 0.f, 0.f};

#pragma unroll
      for (int m = 0; m < 4; ++m) {
        f32x4 a0 = (f32x4){0.f, 0.f, 0.f, 0.f};
        f32x4 a1 = (f32x4){0.f, 0.f, 0.f, 0.f};
#pragma unroll
        for (int kk = 0; kk < 4; ++kk) {
          bfx8 wf0 = *(const bfx8*)(WT1 + ((kk * 8 + 2 * m) * 64 + lane) * 16);
          bfx8 wf1 = *(const bfx8*)(WT1 + ((kk * 8 + 2 * m + 1) * 64 + lane) * 16);
          a0 = MFMA16(wf0, af[kk], a0);
          a1 = MFMA16(wf1, af[kk], a1);
        }
        f4v bv0 = *(const f4v*)(Lb1 + (2 * m) * 16 + g * 4);
        f4v bv1 = *(const f4v*)(Lb1 + (2 * m + 1) * 16 + g * 4);
        // GEMM2 weight frags from global (L1/L2-resident packed table)
        bfx8 wf2[4];
#pragma unroll
        for (int t2 = 0; t2 < 4; ++t2)
          wf2[t2] = *(const bfx8*)(wf2g + ((size_t)((t2 * 4 + m) * 64 + lane)) * 8);
        // relu + pack (slot order) + 3 shfl -> GEMM2 B-frag
        uint_t c0 = pk2(fmaxf(a0[0] + bv0[0], 0.f), fmaxf(a0[1] + bv0[1], 0.f));
        uint_t c1 = pk2(fmaxf(a0[2] + bv0[2], 0.f), fmaxf(a0[3] + bv0[3], 0.f));
        uint_t c2 = pk2(fmaxf(a1[0] + bv1[0], 0.f), fmaxf(a1[1] + bv1[1], 0.f));
        uint_t c3 = pk2(fmaxf(a1[2] + bv1[2], 0.f), fmaxf(a1[3] + bv1[3], 0.f));
        uint_t d1 = __shfl_xor(c1, 16, 64);
        uint_t d2 = __shfl_xor(c2, 32, 64);
        uint_t d3 = __shfl_xor(c3, 48, 64);
        union { uint_t u[4]; bfx8 v; } hf;
        hf.u[0] = c0; hf.u[1] = d1; hf.u[2] = d2; hf.u[3] = d3;
#pragma unroll
        for (int t2 = 0; t2 < 4; ++t2)
          acc2[t2] = MFMA16(wf2[t2], hf.v, acc2[t2]);
      }

      float sacc = 0.f;
#pragma unroll
      for (int t2 = 0; t2 < 4; ++t2) {
        f4v b2v = *(const f4v*)(Lb2 + t2 * 16 + g * 4);
        f4v w3v = *(const f4v*)(Lw3 + t2 * 16 + g * 4);
#pragma unroll
        for (int j = 0; j < 4; ++j) {
          float h = fmaxf(acc2[t2][j] + b2v[j], 0.f);
          sacc = fmaf(h, w3v[j], sacc);
        }
      }
      sacc += __shfl_xor(sacc, 16, 64);
      sacc += __shfl_xor(sacc, 32, 64);
      if (g == 0) outp[((bt0 + it) << 8) + ewq] = sacc + bp3v;

#pragma unroll
      for (int kk = 0; kk < 4; ++kk) af[kk] = afn[kk];
    }
  }
}

// ---------------- launch ----------------

static inline size_t alup(size_t x) { return (x + 511) & ~(size_t)511; }

extern "C" void kernel_launch(void* const* d_in, const int* in_sizes, int n_in,
                              void* d_out, int out_size, void* d_ws, size_t ws_size,
                              hipStream_t stream) {
  const float* x = (const float*)d_in[0];
  const int* ei = (const int*)d_in[1];
  const int* nei = (const int*)d_in[2];
  const float* W1 = (const float*)d_in[3];
  const float* b1 = (const float*)d_in[4];
  const float* W2 = (const float*)d_in[5];
  const float* b2 = (const float*)d_in[6];
  const float* Wp1 = (const float*)d_in[7];
  const float* bp1 = (const float*)d_in[8];
  const float* Wp2 = (const float*)d_in[9];
  const float* bp2 = (const float*)d_in[10];
  const float* Wp3 = (const float*)d_in[11];
  const float* bp3 = (const float*)d_in[12];

  const int N = NODES;
  const int E = in_sizes[1] / 2;

  float* pos = (float*)d_out;
  float* neg = pos + E;
  float* z = pos + (size_t)2 * E;

  char* w = (char*)d_ws;
  size_t off = 0;
  int* deg = (int*)(w + off); off = alup(off + (size_t)N * 4);
  int* cur = (int*)(w + off); off = alup(off + (size_t)N * 4);
  float* dinv = (float*)(w + off); off = alup(off + (size_t)N * 4);
  int* bsum = (int*)(w + off); off = alup(off + 256 * 4);
  int* row_start = (int*)(w + off); off = alup(off + (size_t)(N + 1) * 4);
  int* csr = (int*)(w + off); off = alup(off + (size_t)E * 4);
  float* xw = (float*)(w + off); off = alup(off + (size_t)N * 64 * 4);
  float* z1 = (float*)(w + off); off = alup(off + (size_t)N * 64 * 4);
  ushort_t* zb = (ushort_t*)(w + off); off = alup(off + (size_t)N * 64 * 2);
  ushort_t* wf2g = (ushort_t*)(w + off); off = alup(off + (size_t)1024 * 8 * 2);

  hipMemsetAsync(deg, 0, (size_t)N * 4, stream);
  hipMemsetAsync(cur, 0, (size_t)N * 4, stream);

  count_deg<<<(E + 255) / 256, 256, 0, stream>>>(ei + E, deg, E);
  dinv_k<<<(N + 255) / 256, 256, 0, stream>>>(deg, dinv, N);
  scan_sum<<<SCAN_B, 256, 0, stream>>>(deg, bsum);
  scan_top<<<1, 256, 0, stream>>>(bsum);
  scan_out<<<SCAN_B, 256, 0, stream>>>(deg, bsum, row_start, E);
  fill_csr<<<(E + 255) / 256, 256, 0, stream>>>(ei, ei + E, row_start, cur, csr, E);
  pack_wf2<<<4, 256, 0, stream>>>(Wp2, wf2g);

  conv_gemm<256><<<(N + 31) / 32, 256, 0, stream>>>(x, W1, dinv, xw, N);
  agg_k<<<(N + 3) / 4, 256, 0, stream>>>(xw, row_start, csr, dinv, b1, z1, nullptr, N);
  conv_gemm<64><<<(N + 31) / 32, 256, 0, stream>>>(z1, W2, dinv, xw, N);
  agg_k<<<(N + 3) / 4, 256, 0, stream>>>(xw, row_start, csr, dinv, b2, z, zb, N);

  int nbt = E >> 8;                   // 256-edge tiles (16 waves x 16)
  int gridHalf = (nbt + 3) / 4;       // 4 tiles per block per side
  mlp_kernel<<<2 * gridHalf, 1024, 0, stream>>>(ei, nei, zb, wf2g, Wp1, bp1,
                                                bp2, Wp3, bp3, pos, neg, E, gridHalf);
}

// Round 14
// 570.928 us; speedup vs baseline: 1.1214x; 1.1214x over previous
//
#include <hip/hip_runtime.h>
#include <hip/hip_bf16.h>

#define NODES 100000
#define SCAN_B 200
#define CHUNK 500

typedef __attribute__((ext_vector_type(4))) float f4v;
typedef __attribute__((ext_vector_type(8))) short bfx8;
typedef __attribute__((ext_vector_type(4))) float f32x4;
typedef unsigned short ushort_t;
typedef unsigned int uint_t;

__device__ __forceinline__ ushort_t f2b(float f) {
  union { float f; uint_t u; } v; v.f = f;
  return (ushort_t)((v.u + 0x7fffu + ((v.u >> 16) & 1u)) >> 16);
}
__device__ __forceinline__ float b2f(ushort_t h) {
  union { uint_t u; float f; } v; v.u = ((uint_t)h) << 16;
  return v.f;
}
// packed pair via compiler-fused v_cvt_pk_bf16_f32
__device__ __forceinline__ uint_t pk2(float a, float b) {
  union { __hip_bfloat16 h; ushort_t u; } lo, hi;
  lo.h = __float2bfloat16(a);
  hi.h = __float2bfloat16(b);
  return (uint_t)lo.u | ((uint_t)hi.u << 16);
}

// h1-slot permutation: slot r (GEMM1 D order) -> actual n1 (GEMM2 k order)
__device__ __forceinline__ int permn1(int r) {
  int t = r >> 4, g = (r >> 2) & 3, p = (r >> 1) & 1, e = r & 1;
  int w = 2 * (t & 1) + p;
  return 32 * (t >> 1) + 8 * (g ^ w) + 2 * w + e;
}

#define MFMA16(A, B, C) __builtin_amdgcn_mfma_f32_16x16x32_bf16((A), (B), (C), 0, 0, 0)

// ---------------- graph prep ----------------

__global__ void count_deg(const int* __restrict__ dst, int* __restrict__ deg, int E) {
  int i = blockIdx.x * 256 + threadIdx.x;
  if (i < E) atomicAdd(&deg[dst[i]], 1);
}

__global__ void dinv_k(const int* __restrict__ deg, float* __restrict__ dinv, int n) {
  int i = blockIdx.x * 256 + threadIdx.x;
  if (i < n) dinv[i] = 1.0f / sqrtf((float)(deg[i] + 1));
}

__global__ void scan_sum(const int* __restrict__ deg, int* __restrict__ bsum) {
  __shared__ int sh[256];
  int b = blockIdx.x, t = threadIdx.x;
  int base = b * CHUNK;
  int v = 0;
  for (int i = t; i < CHUNK; i += 256) v += deg[base + i];
  sh[t] = v;
  __syncthreads();
  for (int s = 128; s > 0; s >>= 1) {
    if (t < s) sh[t] += sh[t + s];
    __syncthreads();
  }
  if (t == 0) bsum[b] = sh[0];
}

__global__ void scan_top(int* __restrict__ bsum) {
  __shared__ int sh[SCAN_B];
  int t = threadIdx.x;
  if (t < SCAN_B) sh[t] = bsum[t];
  __syncthreads();
  if (t == 0) {
    int run = 0;
    for (int i = 0; i < SCAN_B; ++i) { int x = sh[i]; sh[i] = run; run += x; }
  }
  __syncthreads();
  if (t < SCAN_B) bsum[t] = sh[t];
}

__global__ void scan_out(const int* __restrict__ deg, const int* __restrict__ bsum,
                         int* __restrict__ row_start, int E) {
  __shared__ int sh[CHUNK];
  int b = blockIdx.x, t = threadIdx.x;
  int base = b * CHUNK;
  for (int i = t; i < CHUNK; i += 256) sh[i] = deg[base + i];
  __syncthreads();
  if (t == 0) {
    int run = bsum[b];
    for (int i = 0; i < CHUNK; ++i) { int x = sh[i]; sh[i] = run; run += x; }
  }
  __syncthreads();
  for (int i = t; i < CHUNK; i += 256) row_start[base + i] = sh[i];
  if (b == SCAN_B - 1 && t == 0) row_start[NODES] = E;
}

__global__ void fill_csr(const int* __restrict__ src, const int* __restrict__ dst,
                         const int* __restrict__ row_start, int* __restrict__ cursor,
                         int* __restrict__ csr, int E) {
  int i = blockIdx.x * 256 + threadIdx.x;
  if (i < E) {
    int d = dst[i];
    int p = atomicAdd(&cursor[d], 1);
    csr[row_start[d] + p] = src[i];
  }
}

// ---------------- conv path: split-bf16 MFMA GEMM ----------------
template <int K>
__global__ __launch_bounds__(256) void conv_gemm(
    const float* __restrict__ A, const float* __restrict__ W,
    const float* __restrict__ dinv, float* __restrict__ out, int n) {
  constexpr int KT = K / 32;
  constexpr int SEGS = K / 8;
  __shared__ __align__(16) ushort_t lhi[32 * K];
  __shared__ __align__(16) ushort_t llo[32 * K];

  int tid = threadIdx.x;
  int lane = tid & 63, wave = tid >> 6;
  int q = lane & 15, g = lane >> 4;
  int c0 = wave * 16;
  int r0 = blockIdx.x * 32;

  bfx8 bhi[KT], blo[KT];
#pragma unroll
  for (int kt = 0; kt < KT; ++kt) {
    bfx8 h, l;
#pragma unroll
    for (int j = 0; j < 8; ++j) {
      float w = W[(size_t)(kt * 32 + g * 8 + j) * 64 + c0 + q];
      ushort_t hb = f2b(w);
      float lo = w - b2f(hb);
      h[j] = (short)hb;
      l[j] = (short)f2b(lo);
    }
    bhi[kt] = h;
    blo[kt] = l;
  }

  for (int idx = tid; idx < 32 * SEGS; idx += 256) {
    int row = idx / SEGS, s = idx % SEGS;
    const float* p = A + (size_t)(r0 + row) * K + s * 8;
    f4v v0 = *(const f4v*)p;
    f4v v1 = *(const f4v*)(p + 4);
    bfx8 h8, l8;
#pragma unroll
    for (int j = 0; j < 4; ++j) {
      ushort_t hb = f2b(v0[j]);
      h8[j] = (short)hb;
      l8[j] = (short)f2b(v0[j] - b2f(hb));
      ushort_t hb1 = f2b(v1[j]);
      h8[4 + j] = (short)hb1;
      l8[4 + j] = (short)f2b(v1[j] - b2f(hb1));
    }
    int boff = row * (K * 2) + ((s * 16) ^ ((row & 7) << 4));
    *(bfx8*)((char*)lhi + boff) = h8;
    *(bfx8*)((char*)llo + boff) = l8;
  }
  __syncthreads();

  f32x4 hh[2], hl[2], lh[2];
#pragma unroll
  for (int rt = 0; rt < 2; ++rt) {
    hh[rt] = (f32x4){0.f, 0.f, 0.f, 0.f};
    hl[rt] = (f32x4){0.f, 0.f, 0.f, 0.f};
    lh[rt] = (f32x4){0.f, 0.f, 0.f, 0.f};
  }
#pragma unroll
  for (int kt = 0; kt < KT; ++kt) {
#pragma unroll
    for (int rt = 0; rt < 2; ++rt) {
      int row = rt * 16 + q;
      int boff = row * (K * 2) + (((kt * 64 + g * 16)) ^ ((row & 7) << 4));
      bfx8 ah = *(const bfx8*)((const char*)lhi + boff);
      bfx8 al = *(const bfx8*)((const char*)llo + boff);
      hh[rt] = MFMA16(ah, bhi[kt], hh[rt]);
      hl[rt] = MFMA16(ah, blo[kt], hl[rt]);
      lh[rt] = MFMA16(al, bhi[kt], lh[rt]);
    }
  }

#pragma unroll
  for (int rt = 0; rt < 2; ++rt) {
    f32x4 s = hh[rt] + hl[rt] + lh[rt];
#pragma unroll
    for (int j = 0; j < 4; ++j) {
      int row = r0 + rt * 16 + g * 4 + j;
      if (row < n) out[(size_t)row * 64 + c0 + q] = s[j] * dinv[row];
    }
  }
}

// out[i][c] = relu( dinv[i] * (P[i][c] + sum_{s in nbr(i)} P[s][c]) + bias[c] )
// 1 node/wave, 64 lanes x 1 float. 16-deep unrolled gather (VGPR=8 leaves
// huge headroom; csr index loads are wave-uniform -> SMEM s_load, off the
// VMEM queue). 8 accumulators.
__global__ void agg_k(const float* __restrict__ P, const int* __restrict__ row_start,
                      const int* __restrict__ csr, const float* __restrict__ dinv,
                      const float* __restrict__ bias, float* __restrict__ out,
                      ushort_t* __restrict__ zb, int n) {
  int wave = threadIdx.x >> 6, lane = threadIdx.x & 63;
  int i = blockIdx.x * 4 + wave;
  if (i >= n) return;
  const float* Pl = P + lane;
  float a0 = Pl[(size_t)i * 64];
  float a1 = 0.f, a2 = 0.f, a3 = 0.f, a4 = 0.f, a5 = 0.f, a6 = 0.f, a7 = 0.f;
  int beg = row_start[i], end = row_start[i + 1];
  int j = beg;
  for (; j + 16 <= end; j += 16) {
    int s[16];
#pragma unroll
    for (int u = 0; u < 16; ++u) s[u] = csr[j + u];
    float v[16];
#pragma unroll
    for (int u = 0; u < 16; ++u) v[u] = Pl[(size_t)s[u] * 64];
    a0 += v[0] + v[8];  a1 += v[1] + v[9];
    a2 += v[2] + v[10]; a3 += v[3] + v[11];
    a4 += v[4] + v[12]; a5 += v[5] + v[13];
    a6 += v[6] + v[14]; a7 += v[7] + v[15];
  }
  if (j + 8 <= end) {
    int s[8];
#pragma unroll
    for (int u = 0; u < 8; ++u) s[u] = csr[j + u];
    float v[8];
#pragma unroll
    for (int u = 0; u < 8; ++u) v[u] = Pl[(size_t)s[u] * 64];
    a0 += v[0]; a1 += v[1]; a2 += v[2]; a3 += v[3];
    a4 += v[4]; a5 += v[5]; a6 += v[6]; a7 += v[7];
    j += 8;
  }
  if (j + 4 <= end) {
    int s0 = csr[j], s1 = csr[j + 1], s2 = csr[j + 2], s3 = csr[j + 3];
    float v0 = Pl[(size_t)s0 * 64];
    float v1 = Pl[(size_t)s1 * 64];
    float v2 = Pl[(size_t)s2 * 64];
    float v3 = Pl[(size_t)s3 * 64];
    a0 += v0; a1 += v1; a2 += v2; a3 += v3;
    j += 4;
  }
  for (; j < end; ++j) a1 += Pl[(size_t)csr[j] * 64];
  float acc = ((a0 + a1) + (a2 + a3)) + ((a4 + a5) + (a6 + a7));
  float v = fmaxf(acc * dinv[i] + bias[lane], 0.0f);
  out[(size_t)i * 64 + lane] = v;
  if (zb) zb[(size_t)i * 64 + lane] = f2b(v);
}

// ---------------- edge MLP (merged pos+neg) — r12-proven config ----------------
// 16 edges/wave-iter, VGPR ~48, 0 bank conflicts, 2-deep prefetch,
// 1024-thr blocks (32 waves/CU). pos+neg in ONE dispatch. WF2 stays in LDS:
// r13 lesson — moving it to global puts its loads behind the feature gathers
// in the in-order vmcnt queue -> each m-iter stalls on full gather latency
// (244 -> 307 us). DS-byte floor of this structure ~= 188 us of 244; accepted.
__global__ __launch_bounds__(1024) void mlp_kernel(
    const int* __restrict__ ei, const int* __restrict__ nei,
    const ushort_t* __restrict__ zb,
    const float* __restrict__ Wp1, const float* __restrict__ bp1,
    const float* __restrict__ Wp2, const float* __restrict__ bp2,
    const float* __restrict__ Wp3, const float* __restrict__ bp3,
    float* __restrict__ pos, float* __restrict__ neg,
    int E, int gridHalf) {
  __shared__ __align__(16) char WT1[32768];   // Wp1 A-frags [kk*8+t][lane]*16B
  __shared__ __align__(16) char WF2[16384];   // Wp2 A-frags [t2*4+kk][lane]*16B
  __shared__ __align__(16) float Lb1[128];    // bp1 permuted to slot order
  __shared__ __align__(16) float Lb2[64];
  __shared__ __align__(16) float Lw3[64];

  int tid = threadIdx.x;
  int lane = tid & 63, wave = tid >> 6;   // wave in [0,16)
  int q = lane & 15, g = lane >> 4;

  for (int idx = tid; idx < 2048; idx += 1024) {
    int l = idx & 63, f = idx >> 6;
    int t = f & 7, kk = f >> 3;
    int lq = l & 15, lg = l >> 4;
    int n1 = permn1(t * 16 + lq);
    bfx8 v;
#pragma unroll
    for (int j = 0; j < 8; ++j)
      v[j] = (short)f2b(Wp1[(kk * 32 + lg * 8 + j) * 128 + n1]);
    *(bfx8*)(WT1 + idx * 16) = v;
  }
  for (int idx = tid; idx < 1024; idx += 1024) {
    int l = idx & 63, fk = idx >> 6;
    int t2 = fk >> 2, kk = fk & 3;
    int lq = l & 15, lg = l >> 4;
    bfx8 v;
#pragma unroll
    for (int j = 0; j < 8; ++j)
      v[j] = (short)f2b(Wp2[(kk * 32 + lg * 8 + j) * 64 + t2 * 16 + lq]);
    *(bfx8*)(WF2 + idx * 16) = v;
  }
  if (tid < 128) Lb1[tid] = bp1[permn1(tid)];
  if (tid < 64) { Lb2[tid] = bp2[tid]; Lw3[tid] = Wp3[tid]; }
  __syncthreads();

  float bp3v = bp3[0];

  int side = (blockIdx.x >= gridHalf) ? 1 : 0;
  const int* eip = side ? nei : ei;
  float* outp = side ? neg : pos;
  int bb = blockIdx.x - side * gridHalf;

  int nbt = E >> 8;              // 256-edge block-tiles (16 waves x 16)
  int bt0 = bb << 2;             // 4 consecutive tiles per block
  int ewq = (wave << 4) + q;     // edge offset within tile [0,256)

  int si[6], di[6];
  bfx8 af[4], afn[4];

  {
    int e = ((bt0 + 0) < nbt) ? (((bt0 + 0) << 8) + ewq) : 0;
    si[0] = eip[e]; di[0] = eip[E + e];
  }
  {
    int e = ((bt0 + 1) < nbt) ? (((bt0 + 1) << 8) + ewq) : 0;
    si[1] = eip[e]; di[1] = eip[E + e];
  }
#pragma unroll
  for (int kk = 0; kk < 4; ++kk) {
    int node = (kk < 2) ? si[0] : di[0];
    af[kk] = *(const bfx8*)(zb + (size_t)node * 64 + ((kk & 1) << 5) + (g << 3));
  }

#pragma unroll
  for (int it = 0; it < 4; ++it) {
    if (bt0 + it < nbt) {
      // prefetch indices for it+2
      if (it + 2 < 4) {
        int e = ((bt0 + it + 2) < nbt) ? (((bt0 + it + 2) << 8) + ewq) : 0;
        si[it + 2] = eip[e]; di[it + 2] = eip[E + e];
      }
      // prefetch features for it+1 (indices issued one iter ago)
      if (it + 1 < 4 && (bt0 + it + 1) < nbt) {
#pragma unroll
        for (int kk = 0; kk < 4; ++kk) {
          int node = (kk < 2) ? si[it + 1] : di[it + 1];
          afn[kk] = *(const bfx8*)(zb + (size_t)node * 64 + ((kk & 1) << 5) + (g << 3));
        }
      } else {
#pragma unroll
        for (int kk = 0; kk < 4; ++kk) afn[kk] = af[kk];
      }

      f32x4 acc2[4];
#pragma unroll
      for (int t2 = 0; t2 < 4; ++t2) acc2[t2] = (f32x4){0.f, 0.f, 0.f, 0.f};

#pragma unroll
      for (int m = 0; m < 4; ++m) {
        f32x4 a0 = (f32x4){0.f, 0.f, 0.f, 0.f};
        f32x4 a1 = (f32x4){0.f, 0.f, 0.f, 0.f};
#pragma unroll
        for (int kk = 0; kk < 4; ++kk) {
          bfx8 wf0 = *(const bfx8*)(WT1 + ((kk * 8 + 2 * m) * 64 + lane) * 16);
          bfx8 wf1 = *(const bfx8*)(WT1 + ((kk * 8 + 2 * m + 1) * 64 + lane) * 16);
          a0 = MFMA16(wf0, af[kk], a0);
          a1 = MFMA16(wf1, af[kk], a1);
        }
        f4v bv0 = *(const f4v*)(Lb1 + (2 * m) * 16 + g * 4);
        f4v bv1 = *(const f4v*)(Lb1 + (2 * m + 1) * 16 + g * 4);
        bfx8 wf2[4];
#pragma unroll
        for (int t2 = 0; t2 < 4; ++t2)
          wf2[t2] = *(const bfx8*)(WF2 + ((t2 * 4 + m) * 64 + lane) * 16);
        // relu + pack (slot order) + 3 shfl -> GEMM2 B-frag
        uint_t c0 = pk2(fmaxf(a0[0] + bv0[0], 0.f), fmaxf(a0[1] + bv0[1], 0.f));
        uint_t c1 = pk2(fmaxf(a0[2] + bv0[2], 0.f), fmaxf(a0[3] + bv0[3], 0.f));
        uint_t c2 = pk2(fmaxf(a1[0] + bv1[0], 0.f), fmaxf(a1[1] + bv1[1], 0.f));
        uint_t c3 = pk2(fmaxf(a1[2] + bv1[2], 0.f), fmaxf(a1[3] + bv1[3], 0.f));
        uint_t d1 = __shfl_xor(c1, 16, 64);
        uint_t d2 = __shfl_xor(c2, 32, 64);
        uint_t d3 = __shfl_xor(c3, 48, 64);
        union { uint_t u[4]; bfx8 v; } hf;
        hf.u[0] = c0; hf.u[1] = d1; hf.u[2] = d2; hf.u[3] = d3;
#pragma unroll
        for (int t2 = 0; t2 < 4; ++t2)
          acc2[t2] = MFMA16(wf2[t2], hf.v, acc2[t2]);
      }

      float sacc = 0.f;
#pragma unroll
      for (int t2 = 0; t2 < 4; ++t2) {
        f4v b2v = *(const f4v*)(Lb2 + t2 * 16 + g * 4);
        f4v w3v = *(const f4v*)(Lw3 + t2 * 16 + g * 4);
#pragma unroll
        for (int j = 0; j < 4; ++j) {
          float h = fmaxf(acc2[t2][j] + b2v[j], 0.f);
          sacc = fmaf(h, w3v[j], sacc);
        }
      }
      sacc += __shfl_xor(sacc, 16, 64);
      sacc += __shfl_xor(sacc, 32, 64);
      if (g == 0) outp[((bt0 + it) << 8) + ewq] = sacc + bp3v;

#pragma unroll
      for (int kk = 0; kk < 4; ++kk) af[kk] = afn[kk];
    }
  }
}

// ---------------- launch ----------------

static inline size_t alup(size_t x) { return (x + 511) & ~(size_t)511; }

extern "C" void kernel_launch(void* const* d_in, const int* in_sizes, int n_in,
                              void* d_out, int out_size, void* d_ws, size_t ws_size,
                              hipStream_t stream) {
  const float* x = (const float*)d_in[0];
  const int* ei = (const int*)d_in[1];
  const int* nei = (const int*)d_in[2];
  const float* W1 = (const float*)d_in[3];
  const float* b1 = (const float*)d_in[4];
  const float* W2 = (const float*)d_in[5];
  const float* b2 = (const float*)d_in[6];
  const float* Wp1 = (const float*)d_in[7];
  const float* bp1 = (const float*)d_in[8];
  const float* Wp2 = (const float*)d_in[9];
  const float* bp2 = (const float*)d_in[10];
  const float* Wp3 = (const float*)d_in[11];
  const float* bp3 = (const float*)d_in[12];

  const int N = NODES;
  const int E = in_sizes[1] / 2;

  float* pos = (float*)d_out;
  float* neg = pos + E;
  float* z = pos + (size_t)2 * E;

  char* w = (char*)d_ws;
  size_t off = 0;
  int* deg = (int*)(w + off); off = alup(off + (size_t)N * 4);
  int* cur = (int*)(w + off); off = alup(off + (size_t)N * 4);
  float* dinv = (float*)(w + off); off = alup(off + (size_t)N * 4);
  int* bsum = (int*)(w + off); off = alup(off + 256 * 4);
  int* row_start = (int*)(w + off); off = alup(off + (size_t)(N + 1) * 4);
  int* csr = (int*)(w + off); off = alup(off + (size_t)E * 4);
  float* xw = (float*)(w + off); off = alup(off + (size_t)N * 64 * 4);
  float* z1 = (float*)(w + off); off = alup(off + (size_t)N * 64 * 4);
  ushort_t* zb = (ushort_t*)(w + off); off = alup(off + (size_t)N * 64 * 2);

  hipMemsetAsync(deg, 0, (size_t)N * 4, stream);
  hipMemsetAsync(cur, 0, (size_t)N * 4, stream);

  count_deg<<<(E + 255) / 256, 256, 0, stream>>>(ei + E, deg, E);
  dinv_k<<<(N + 255) / 256, 256, 0, stream>>>(deg, dinv, N);
  scan_sum<<<SCAN_B, 256, 0, stream>>>(deg, bsum);
  scan_top<<<1, 256, 0, stream>>>(bsum);
  scan_out<<<SCAN_B, 256, 0, stream>>>(deg, bsum, row_start, E);
  fill_csr<<<(E + 255) / 256, 256, 0, stream>>>(ei, ei + E, row_start, cur, csr, E);

  conv_gemm<256><<<(N + 31) / 32, 256, 0, stream>>>(x, W1, dinv, xw, N);
  agg_k<<<(N + 3) / 4, 256, 0, stream>>>(xw, row_start, csr, dinv, b1, z1, nullptr, N);
  conv_gemm<64><<<(N + 31) / 32, 256, 0, stream>>>(z1, W2, dinv, xw, N);
  agg_k<<<(N + 3) / 4, 256, 0, stream>>>(xw, row_start, csr, dinv, b2, z, zb, N);

  int nbt = E >> 8;                   // 256-edge tiles (16 waves x 16)
  int gridHalf = (nbt + 3) / 4;       // 4 tiles per block per side
  mlp_kernel<<<2 * gridHalf, 1024, 0, stream>>>(ei, nei, zb, Wp1, bp1, Wp2, bp2,
                                                Wp3, bp3, pos, neg, E, gridHalf);
}

// Round 15
// 556.986 us; speedup vs baseline: 1.1495x; 1.0250x over previous
//
#include <hip/hip_runtime.h>
#include <hip/hip_bf16.h>

#define NODES 100000
#define SCAN_B 200
#define CHUNK 500

typedef __attribute__((ext_vector_type(4))) float f4v;
typedef __attribute__((ext_vector_type(8))) short bfx8;
typedef __attribute__((ext_vector_type(4))) float f32x4;
typedef unsigned short ushort_t;
typedef unsigned int uint_t;

__device__ __forceinline__ ushort_t f2b(float f) {
  union { float f; uint_t u; } v; v.f = f;
  return (ushort_t)((v.u + 0x7fffu + ((v.u >> 16) & 1u)) >> 16);
}
__device__ __forceinline__ float b2f(ushort_t h) {
  union { uint_t u; float f; } v; v.u = ((uint_t)h) << 16;
  return v.f;
}
// packed pair via compiler-fused v_cvt_pk_bf16_f32
__device__ __forceinline__ uint_t pk2(float a, float b) {
  union { __hip_bfloat16 h; ushort_t u; } lo, hi;
  lo.h = __float2bfloat16(a);
  hi.h = __float2bfloat16(b);
  return (uint_t)lo.u | ((uint_t)hi.u << 16);
}

// h1-slot permutation: slot r (GEMM1 D order) -> actual n1 (GEMM2 k order)
__device__ __forceinline__ int permn1(int r) {
  int t = r >> 4, g = (r >> 2) & 3, p = (r >> 1) & 1, e = r & 1;
  int w = 2 * (t & 1) + p;
  return 32 * (t >> 1) + 8 * (g ^ w) + 2 * w + e;
}

#define MFMA16(A, B, C) __builtin_amdgcn_mfma_f32_16x16x32_bf16((A), (B), (C), 0, 0, 0)

// ---------------- graph prep ----------------

__global__ void count_deg(const int* __restrict__ dst, int* __restrict__ deg, int E) {
  int i = blockIdx.x * 256 + threadIdx.x;
  if (i < E) atomicAdd(&deg[dst[i]], 1);
}

__global__ void dinv_k(const int* __restrict__ deg, float* __restrict__ dinv, int n) {
  int i = blockIdx.x * 256 + threadIdx.x;
  if (i < n) dinv[i] = 1.0f / sqrtf((float)(deg[i] + 1));
}

__global__ void scan_sum(const int* __restrict__ deg, int* __restrict__ bsum) {
  __shared__ int sh[256];
  int b = blockIdx.x, t = threadIdx.x;
  int base = b * CHUNK;
  int v = 0;
  for (int i = t; i < CHUNK; i += 256) v += deg[base + i];
  sh[t] = v;
  __syncthreads();
  for (int s = 128; s > 0; s >>= 1) {
    if (t < s) sh[t] += sh[t + s];
    __syncthreads();
  }
  if (t == 0) bsum[b] = sh[0];
}

__global__ void scan_top(int* __restrict__ bsum) {
  __shared__ int sh[SCAN_B];
  int t = threadIdx.x;
  if (t < SCAN_B) sh[t] = bsum[t];
  __syncthreads();
  if (t == 0) {
    int run = 0;
    for (int i = 0; i < SCAN_B; ++i) { int x = sh[i]; sh[i] = run; run += x; }
  }
  __syncthreads();
  if (t < SCAN_B) bsum[t] = sh[t];
}

__global__ void scan_out(const int* __restrict__ deg, const int* __restrict__ bsum,
                         int* __restrict__ row_start, int E) {
  __shared__ int sh[CHUNK];
  int b = blockIdx.x, t = threadIdx.x;
  int base = b * CHUNK;
  for (int i = t; i < CHUNK; i += 256) sh[i] = deg[base + i];
  __syncthreads();
  if (t == 0) {
    int run = bsum[b];
    for (int i = 0; i < CHUNK; ++i) { int x = sh[i]; sh[i] = run; run += x; }
  }
  __syncthreads();
  for (int i = t; i < CHUNK; i += 256) row_start[base + i] = sh[i];
  if (b == SCAN_B - 1 && t == 0) row_start[NODES] = E;
}

__global__ void fill_csr(const int* __restrict__ src, const int* __restrict__ dst,
                         const int* __restrict__ row_start, int* __restrict__ cursor,
                         int* __restrict__ csr, int E) {
  int i = blockIdx.x * 256 + threadIdx.x;
  if (i < E) {
    int d = dst[i];
    int p = atomicAdd(&cursor[d], 1);
    csr[row_start[d] + p] = src[i];
  }
}

// ---------------- conv layer 1: split-bf16 MFMA GEMM (fp32 A) ----------------
template <int K>
__global__ __launch_bounds__(256) void conv_gemm(
    const float* __restrict__ A, const float* __restrict__ W,
    const float* __restrict__ dinv, float* __restrict__ out, int n) {
  constexpr int KT = K / 32;
  constexpr int SEGS = K / 8;
  __shared__ __align__(16) ushort_t lhi[32 * K];
  __shared__ __align__(16) ushort_t llo[32 * K];

  int tid = threadIdx.x;
  int lane = tid & 63, wave = tid >> 6;
  int q = lane & 15, g = lane >> 4;
  int c0 = wave * 16;
  int r0 = blockIdx.x * 32;

  bfx8 bhi[KT], blo[KT];
#pragma unroll
  for (int kt = 0; kt < KT; ++kt) {
    bfx8 h, l;
#pragma unroll
    for (int j = 0; j < 8; ++j) {
      float w = W[(size_t)(kt * 32 + g * 8 + j) * 64 + c0 + q];
      ushort_t hb = f2b(w);
      float lo = w - b2f(hb);
      h[j] = (short)hb;
      l[j] = (short)f2b(lo);
    }
    bhi[kt] = h;
    blo[kt] = l;
  }

  for (int idx = tid; idx < 32 * SEGS; idx += 256) {
    int row = idx / SEGS, s = idx % SEGS;
    const float* p = A + (size_t)(r0 + row) * K + s * 8;
    f4v v0 = *(const f4v*)p;
    f4v v1 = *(const f4v*)(p + 4);
    bfx8 h8, l8;
#pragma unroll
    for (int j = 0; j < 4; ++j) {
      ushort_t hb = f2b(v0[j]);
      h8[j] = (short)hb;
      l8[j] = (short)f2b(v0[j] - b2f(hb));
      ushort_t hb1 = f2b(v1[j]);
      h8[4 + j] = (short)hb1;
      l8[4 + j] = (short)f2b(v1[j] - b2f(hb1));
    }
    int boff = row * (K * 2) + ((s * 16) ^ ((row & 7) << 4));
    *(bfx8*)((char*)lhi + boff) = h8;
    *(bfx8*)((char*)llo + boff) = l8;
  }
  __syncthreads();

  f32x4 hh[2], hl[2], lh[2];
#pragma unroll
  for (int rt = 0; rt < 2; ++rt) {
    hh[rt] = (f32x4){0.f, 0.f, 0.f, 0.f};
    hl[rt] = (f32x4){0.f, 0.f, 0.f, 0.f};
    lh[rt] = (f32x4){0.f, 0.f, 0.f, 0.f};
  }
#pragma unroll
  for (int kt = 0; kt < KT; ++kt) {
#pragma unroll
    for (int rt = 0; rt < 2; ++rt) {
      int row = rt * 16 + q;
      int boff = row * (K * 2) + (((kt * 64 + g * 16)) ^ ((row & 7) << 4));
      bfx8 ah = *(const bfx8*)((const char*)lhi + boff);
      bfx8 al = *(const bfx8*)((const char*)llo + boff);
      hh[rt] = MFMA16(ah, bhi[kt], hh[rt]);
      hl[rt] = MFMA16(ah, blo[kt], hl[rt]);
      lh[rt] = MFMA16(al, bhi[kt], lh[rt]);
    }
  }

#pragma unroll
  for (int rt = 0; rt < 2; ++rt) {
    f32x4 s = hh[rt] + hl[rt] + lh[rt];
#pragma unroll
    for (int j = 0; j < 4; ++j) {
      int row = r0 + rt * 16 + g * 4 + j;
      if (row < n) out[(size_t)row * 64 + c0 + q] = s[j] * dinv[row];
    }
  }
}

// ---------------- conv layer 2: bf16 A input (K=64) ----------------
// A arrives as bf16 (z1 stored bf16-only): staging is a raw copy (no split
// VALU), and the A-lo MFMA chain vanishes (4 MFMA/kt-pair vs 6).
__global__ __launch_bounds__(256) void conv_gemm2(
    const ushort_t* __restrict__ Ab, const float* __restrict__ W,
    const float* __restrict__ dinv, float* __restrict__ out, int n) {
  __shared__ __align__(16) ushort_t lA[32 * 64];

  int tid = threadIdx.x;
  int lane = tid & 63, wave = tid >> 6;
  int q = lane & 15, g = lane >> 4;
  int c0 = wave * 16;
  int r0 = blockIdx.x * 32;

  bfx8 bhi[2], blo[2];
#pragma unroll
  for (int kt = 0; kt < 2; ++kt) {
    bfx8 h, l;
#pragma unroll
    for (int j = 0; j < 8; ++j) {
      float w = W[(size_t)(kt * 32 + g * 8 + j) * 64 + c0 + q];
      ushort_t hb = f2b(w);
      float lo = w - b2f(hb);
      h[j] = (short)hb;
      l[j] = (short)f2b(lo);
    }
    bhi[kt] = h;
    blo[kt] = l;
  }

  {
    int idx = tid;  // 256 entries, one per thread
    int row = idx >> 3, s = idx & 7;
    bfx8 v = *(const bfx8*)(Ab + (size_t)(r0 + row) * 64 + s * 8);
    int boff = row * 128 + ((s * 16) ^ ((row & 7) << 4));
    *(bfx8*)((char*)lA + boff) = v;
  }
  __syncthreads();

  f32x4 hh[2], hl[2];
#pragma unroll
  for (int rt = 0; rt < 2; ++rt) {
    hh[rt] = (f32x4){0.f, 0.f, 0.f, 0.f};
    hl[rt] = (f32x4){0.f, 0.f, 0.f, 0.f};
  }
#pragma unroll
  for (int kt = 0; kt < 2; ++kt) {
#pragma unroll
    for (int rt = 0; rt < 2; ++rt) {
      int row = rt * 16 + q;
      int boff = row * 128 + (((kt * 64 + g * 16)) ^ ((row & 7) << 4));
      bfx8 ah = *(const bfx8*)((const char*)lA + boff);
      hh[rt] = MFMA16(ah, bhi[kt], hh[rt]);
      hl[rt] = MFMA16(ah, blo[kt], hl[rt]);
    }
  }

#pragma unroll
  for (int rt = 0; rt < 2; ++rt) {
    f32x4 s = hh[rt] + hl[rt];
#pragma unroll
    for (int j = 0; j < 4; ++j) {
      int row = r0 + rt * 16 + g * 4 + j;
      if (row < n) out[(size_t)row * 64 + c0 + q] = s[j] * dinv[row];
    }
  }
}

// out[i][c] = relu( dinv[i] * (P[i][c] + sum_{s in nbr(i)} P[s][c]) + bias[c] )
// r10-proven: 1 node/wave, 8-wide unrolled gather. fp32 out and bf16 zb
// both optional.
__global__ void agg_k(const float* __restrict__ P, const int* __restrict__ row_start,
                      const int* __restrict__ csr, const float* __restrict__ dinv,
                      const float* __restrict__ bias, float* __restrict__ out,
                      ushort_t* __restrict__ zb, int n) {
  int wave = threadIdx.x >> 6, lane = threadIdx.x & 63;
  int i = blockIdx.x * 4 + wave;
  if (i >= n) return;
  const float* Pl = P + lane;
  float a0 = Pl[(size_t)i * 64];
  float a1 = 0.f, a2 = 0.f, a3 = 0.f;
  int beg = row_start[i], end = row_start[i + 1];
  int j = beg;
  for (; j + 8 <= end; j += 8) {
    int s0 = csr[j + 0], s1 = csr[j + 1], s2 = csr[j + 2], s3 = csr[j + 3];
    int s4 = csr[j + 4], s5 = csr[j + 5], s6 = csr[j + 6], s7 = csr[j + 7];
    float v0 = Pl[(size_t)s0 * 64];
    float v1 = Pl[(size_t)s1 * 64];
    float v2 = Pl[(size_t)s2 * 64];
    float v3 = Pl[(size_t)s3 * 64];
    float v4 = Pl[(size_t)s4 * 64];
    float v5 = Pl[(size_t)s5 * 64];
    float v6 = Pl[(size_t)s6 * 64];
    float v7 = Pl[(size_t)s7 * 64];
    a0 += v0; a1 += v1; a2 += v2; a3 += v3;
    a0 += v4; a1 += v5; a2 += v6; a3 += v7;
  }
  if (j + 4 <= end) {
    int s0 = csr[j + 0], s1 = csr[j + 1], s2 = csr[j + 2], s3 = csr[j + 3];
    float v0 = Pl[(size_t)s0 * 64];
    float v1 = Pl[(size_t)s1 * 64];
    float v2 = Pl[(size_t)s2 * 64];
    float v3 = Pl[(size_t)s3 * 64];
    a0 += v0; a1 += v1; a2 += v2; a3 += v3;
    j += 4;
  }
  for (; j < end; ++j) a1 += Pl[(size_t)csr[j] * 64];
  float acc = (a0 + a1) + (a2 + a3);
  float v = fmaxf(acc * dinv[i] + bias[lane], 0.0f);
  if (out) out[(size_t)i * 64 + lane] = v;
  if (zb) zb[(size_t)i * 64 + lane] = f2b(v);
}

// ---------------- edge MLP — r10-proven config (separate dispatches) --------
// 16 edges/wave-iter, VGPR ~48, 0 bank conflicts, 2-deep prefetch,
// 1024-thr blocks (32 waves/CU). Separate pos/neg dispatches: r12/r14
// measured the merged variant as a totals regression (+7us) despite lower
// kernel time. WF2 stays in LDS (r13 vmcnt-ordering lesson).
__global__ __launch_bounds__(1024) void mlp_kernel(
    const int* __restrict__ ei, const ushort_t* __restrict__ zb,
    const float* __restrict__ Wp1, const float* __restrict__ bp1,
    const float* __restrict__ Wp2, const float* __restrict__ bp2,
    const float* __restrict__ Wp3, const float* __restrict__ bp3,
    float* __restrict__ out, int E) {
  __shared__ __align__(16) char WT1[32768];   // Wp1 A-frags [kk*8+t][lane]*16B
  __shared__ __align__(16) char WF2[16384];   // Wp2 A-frags [t2*4+kk][lane]*16B
  __shared__ __align__(16) float Lb1[128];    // bp1 permuted to slot order
  __shared__ __align__(16) float Lb2[64];
  __shared__ __align__(16) float Lw3[64];

  int tid = threadIdx.x;
  int lane = tid & 63, wave = tid >> 6;   // wave in [0,16)
  int q = lane & 15, g = lane >> 4;

  for (int idx = tid; idx < 2048; idx += 1024) {
    int l = idx & 63, f = idx >> 6;
    int t = f & 7, kk = f >> 3;
    int lq = l & 15, lg = l >> 4;
    int n1 = permn1(t * 16 + lq);
    bfx8 v;
#pragma unroll
    for (int j = 0; j < 8; ++j)
      v[j] = (short)f2b(Wp1[(kk * 32 + lg * 8 + j) * 128 + n1]);
    *(bfx8*)(WT1 + idx * 16) = v;
  }
  for (int idx = tid; idx < 1024; idx += 1024) {
    int l = idx & 63, fk = idx >> 6;
    int t2 = fk >> 2, kk = fk & 3;
    int lq = l & 15, lg = l >> 4;
    bfx8 v;
#pragma unroll
    for (int j = 0; j < 8; ++j)
      v[j] = (short)f2b(Wp2[(kk * 32 + lg * 8 + j) * 64 + t2 * 16 + lq]);
    *(bfx8*)(WF2 + idx * 16) = v;
  }
  if (tid < 128) Lb1[tid] = bp1[permn1(tid)];
  if (tid < 64) { Lb2[tid] = bp2[tid]; Lw3[tid] = Wp3[tid]; }
  __syncthreads();

  float bp3v = bp3[0];

  int nbt = E >> 8;              // 256-edge block-tiles (16 waves x 16)
  int bt0 = blockIdx.x << 2;     // 4 consecutive tiles per block
  int ewq = (wave << 4) + q;     // edge offset within tile [0,256)

  int si[6], di[6];
  bfx8 af[4], afn[4];

  {
    int e = ((bt0 + 0) < nbt) ? (((bt0 + 0) << 8) + ewq) : 0;
    si[0] = ei[e]; di[0] = ei[E + e];
  }
  {
    int e = ((bt0 + 1) < nbt) ? (((bt0 + 1) << 8) + ewq) : 0;
    si[1] = ei[e]; di[1] = ei[E + e];
  }
#pragma unroll
  for (int kk = 0; kk < 4; ++kk) {
    int node = (kk < 2) ? si[0] : di[0];
    af[kk] = *(const bfx8*)(zb + (size_t)node * 64 + ((kk & 1) << 5) + (g << 3));
  }

#pragma unroll
  for (int it = 0; it < 4; ++it) {
    if (bt0 + it < nbt) {
      // prefetch indices for it+2
      if (it + 2 < 4) {
        int e = ((bt0 + it + 2) < nbt) ? (((bt0 + it + 2) << 8) + ewq) : 0;
        si[it + 2] = ei[e]; di[it + 2] = ei[E + e];
      }
      // prefetch features for it+1 (indices issued one iter ago)
      if (it + 1 < 4 && (bt0 + it + 1) < nbt) {
#pragma unroll
        for (int kk = 0; kk < 4; ++kk) {
          int node = (kk < 2) ? si[it + 1] : di[it + 1];
          afn[kk] = *(const bfx8*)(zb + (size_t)node * 64 + ((kk & 1) << 5) + (g << 3));
        }
      } else {
#pragma unroll
        for (int kk = 0; kk < 4; ++kk) afn[kk] = af[kk];
      }

      f32x4 acc2[4];
#pragma unroll
      for (int t2 = 0; t2 < 4; ++t2) acc2[t2] = (f32x4){0.f, 0.f, 0.f, 0.f};

#pragma unroll
      for (int m = 0; m < 4; ++m) {
        f32x4 a0 = (f32x4){0.f, 0.f, 0.f, 0.f};
        f32x4 a1 = (f32x4){0.f, 0.f, 0.f, 0.f};
#pragma unroll
        for (int kk = 0; kk < 4; ++kk) {
          bfx8 wf0 = *(const bfx8*)(WT1 + ((kk * 8 + 2 * m) * 64 + lane) * 16);
          bfx8 wf1 = *(const bfx8*)(WT1 + ((kk * 8 + 2 * m + 1) * 64 + lane) * 16);
          a0 = MFMA16(wf0, af[kk], a0);
          a1 = MFMA16(wf1, af[kk], a1);
        }
        f4v bv0 = *(const f4v*)(Lb1 + (2 * m) * 16 + g * 4);
        f4v bv1 = *(const f4v*)(Lb1 + (2 * m + 1) * 16 + g * 4);
        bfx8 wf2[4];
#pragma unroll
        for (int t2 = 0; t2 < 4; ++t2)
          wf2[t2] = *(const bfx8*)(WF2 + ((t2 * 4 + m) * 64 + lane) * 16);
        // relu + pack (slot order) + 3 shfl -> GEMM2 B-frag
        uint_t c0 = pk2(fmaxf(a0[0] + bv0[0], 0.f), fmaxf(a0[1] + bv0[1], 0.f));
        uint_t c1 = pk2(fmaxf(a0[2] + bv0[2], 0.f), fmaxf(a0[3] + bv0[3], 0.f));
        uint_t c2 = pk2(fmaxf(a1[0] + bv1[0], 0.f), fmaxf(a1[1] + bv1[1], 0.f));
        uint_t c3 = pk2(fmaxf(a1[2] + bv1[2], 0.f), fmaxf(a1[3] + bv1[3], 0.f));
        uint_t d1 = __shfl_xor(c1, 16, 64);
        uint_t d2 = __shfl_xor(c2, 32, 64);
        uint_t d3 = __shfl_xor(c3, 48, 64);
        union { uint_t u[4]; bfx8 v; } hf;
        hf.u[0] = c0; hf.u[1] = d1; hf.u[2] = d2; hf.u[3] = d3;
#pragma unroll
        for (int t2 = 0; t2 < 4; ++t2)
          acc2[t2] = MFMA16(wf2[t2], hf.v, acc2[t2]);
      }

      float sacc = 0.f;
#pragma unroll
      for (int t2 = 0; t2 < 4; ++t2) {
        f4v b2v = *(const f4v*)(Lb2 + t2 * 16 + g * 4);
        f4v w3v = *(const f4v*)(Lw3 + t2 * 16 + g * 4);
#pragma unroll
        for (int j = 0; j < 4; ++j) {
          float h = fmaxf(acc2[t2][j] + b2v[j], 0.f);
          sacc = fmaf(h, w3v[j], sacc);
        }
      }
      sacc += __shfl_xor(sacc, 16, 64);
      sacc += __shfl_xor(sacc, 32, 64);
      if (g == 0) out[((bt0 + it) << 8) + ewq] = sacc + bp3v;

#pragma unroll
      for (int kk = 0; kk < 4; ++kk) af[kk] = afn[kk];
    }
  }
}

// ---------------- launch ----------------

static inline size_t alup(size_t x) { return (x + 511) & ~(size_t)511; }

extern "C" void kernel_launch(void* const* d_in, const int* in_sizes, int n_in,
                              void* d_out, int out_size, void* d_ws, size_t ws_size,
                              hipStream_t stream) {
  const float* x = (const float*)d_in[0];
  const int* ei = (const int*)d_in[1];
  const int* nei = (const int*)d_in[2];
  const float* W1 = (const float*)d_in[3];
  const float* b1 = (const float*)d_in[4];
  const float* W2 = (const float*)d_in[5];
  const float* b2 = (const float*)d_in[6];
  const float* Wp1 = (const float*)d_in[7];
  const float* bp1 = (const float*)d_in[8];
  const float* Wp2 = (const float*)d_in[9];
  const float* bp2 = (const float*)d_in[10];
  const float* Wp3 = (const float*)d_in[11];
  const float* bp3 = (const float*)d_in[12];

  const int N = NODES;
  const int E = in_sizes[1] / 2;

  float* pos = (float*)d_out;
  float* neg = pos + E;
  float* z = pos + (size_t)2 * E;

  char* w = (char*)d_ws;
  size_t off = 0;
  int* deg = (int*)(w + off); off = alup(off + (size_t)N * 4);
  int* cur = (int*)(w + off); off = alup(off + (size_t)N * 4);
  float* dinv = (float*)(w + off); off = alup(off + (size_t)N * 4);
  int* bsum = (int*)(w + off); off = alup(off + 256 * 4);
  int* row_start = (int*)(w + off); off = alup(off + (size_t)(N + 1) * 4);
  int* csr = (int*)(w + off); off = alup(off + (size_t)E * 4);
  float* xw = (float*)(w + off); off = alup(off + (size_t)N * 64 * 4);
  ushort_t* zb1 = (ushort_t*)(w + off); off = alup(off + (size_t)N * 64 * 2);
  ushort_t* zb = (ushort_t*)(w + off); off = alup(off + (size_t)N * 64 * 2);

  hipMemsetAsync(deg, 0, (size_t)N * 4, stream);
  hipMemsetAsync(cur, 0, (size_t)N * 4, stream);

  count_deg<<<(E + 255) / 256, 256, 0, stream>>>(ei + E, deg, E);
  dinv_k<<<(N + 255) / 256, 256, 0, stream>>>(deg, dinv, N);
  scan_sum<<<SCAN_B, 256, 0, stream>>>(deg, bsum);
  scan_top<<<1, 256, 0, stream>>>(bsum);
  scan_out<<<SCAN_B, 256, 0, stream>>>(deg, bsum, row_start, E);
  fill_csr<<<(E + 255) / 256, 256, 0, stream>>>(ei, ei + E, row_start, cur, csr, E);

  conv_gemm<256><<<(N + 31) / 32, 256, 0, stream>>>(x, W1, dinv, xw, N);
  agg_k<<<(N + 3) / 4, 256, 0, stream>>>(xw, row_start, csr, dinv, b1, nullptr, zb1, N);
  conv_gemm2<<<(N + 31) / 32, 256, 0, stream>>>(zb1, W2, dinv, xw, N);
  agg_k<<<(N + 3) / 4, 256, 0, stream>>>(xw, row_start, csr, dinv, b2, z, zb, N);

  int nbt = E >> 8;               // 256-edge tiles (16 waves x 16)
  int grid = (nbt + 3) / 4;       // 4 tiles per block
  mlp_kernel<<<grid, 1024, 0, stream>>>(ei, zb, Wp1, bp1, Wp2, bp2, Wp3, bp3, pos, E);
  mlp_kernel<<<grid, 1024, 0, stream>>>(nei, zb, Wp1, bp1, Wp2, bp2, Wp3, bp3, neg, E);
}